// Round 4
// baseline (601.144 us; speedup 1.0000x reference)
//
#include <hip/hip_runtime.h>
#include <math.h>

#define WL_LAYERS 3
#define HSLOTS (1u << 18)
#define HMASK  (HSLOTS - 1u)
#define SCHUNK 1024   // nodes per lookback-scan block
#define ACHUNK 8192   // adj entries staged in LDS per tile (32 KB)

typedef unsigned long long u64;

// lookback descriptor set (one per concurrently-active scan)
struct LB { u64 desc[128]; int done[128]; int ctrs[4]; };

#define AGENT __HIP_MEMORY_SCOPE_AGENT

__device__ __forceinline__ u64 mix64(u64 x) {
    x += 0x9e3779b97f4a7c15ULL;
    x = (x ^ (x >> 30)) * 0xbf58476d1ce4e5b9ULL;
    x = (x ^ (x >> 27)) * 0x94d049bb133111ebULL;
    return x ^ (x >> 31);
}

// zero deg + both lookback sets; base[0]=0
__global__ void k_setup(int* __restrict__ deg, LB* __restrict__ lbA, LB* __restrict__ lbB,
                        long long* __restrict__ scalars, int n) {
    int i = blockIdx.x * blockDim.x + threadIdx.x;
    int T = gridDim.x * blockDim.x;
    for (int j = i; j < n; j += T) deg[j] = 0;
    if (i < 128) { lbA->desc[i] = 0ULL; lbB->desc[i] = 0ULL; lbA->done[i] = 0; lbB->done[i] = 0; }
    if (i < 4) { lbA->ctrs[i] = 0; lbB->ctrs[i] = 0; }
    if (i == 0) scalars[3] = 0;
}

// in-degree count; fused zero of 614MB d_out (hidden under the atomic latency) + layer-0 tables
__global__ void k_count(const int* __restrict__ dst, int* __restrict__ deg,
                        u64* __restrict__ ktab, int* __restrict__ gmin,
                        float* __restrict__ zbuf, long long zn, int E) {
    int tid = blockIdx.x * blockDim.x + threadIdx.x;
    int T = gridDim.x * blockDim.x;
    for (int j = tid; j < (int)HSLOTS; j += T) { ktab[j] = 0ULL; gmin[j] = 0x7fffffff; }
    long long n4 = zn >> 2;
    float4* z4 = (float4*)zbuf;
    for (long long j = tid; j < n4; j += (long long)T)
        z4[j] = make_float4(0.f, 0.f, 0.f, 0.f);
    if (tid < (int)(zn & 3)) zbuf[(n4 << 2) + tid] = 0.f;
    if (tid < E) atomicAdd(&deg[dst[tid]], 1);
}

// single-pass exclusive scan of deg -> absolute offp (decoupled lookback, ticket-ordered);
// fused: zero cursor
__global__ void k_scanoff(const int* __restrict__ deg, int* __restrict__ offp,
                          int* __restrict__ cursor, LB* __restrict__ lb, int n) {
    __shared__ int s[256];
    __shared__ int sh_tkt, sh_ex;
    int t = threadIdx.x;
    if (t == 0) sh_tkt = atomicAdd(&lb->ctrs[0], 1);
    __syncthreads();
    int tkt = sh_tkt;
    int idx0 = tkt * SCHUNK + t * 4;
    int v[4]; int sum = 0;
#pragma unroll
    for (int j = 0; j < 4; ++j) { int ii = idx0 + j; v[j] = (ii < n) ? deg[ii] : 0; sum += v[j]; }
    s[t] = sum; __syncthreads();
    for (int off = 1; off < 256; off <<= 1) {
        int x = (t >= off) ? s[t - off] : 0;
        __syncthreads(); s[t] += x; __syncthreads();
    }
    int lex = s[t] - sum;
    int S = s[255];
    if (t == 0) {
        __hip_atomic_store(&lb->desc[tkt], (1ULL << 62) | (u64)(unsigned)S, __ATOMIC_RELEASE, AGENT);
        int ex = 0;
        for (int b = tkt - 1; b >= 0;) {  // waits only on lower tickets = already-running blocks
            u64 d = __hip_atomic_load(&lb->desc[b], __ATOMIC_ACQUIRE, AGENT);
            unsigned st = (unsigned)(d >> 62);
            if (st == 2u) { ex += (int)(d & 0xffffffffu); break; }
            if (st == 1u) { ex += (int)(d & 0xffffffffu); --b; }
        }
        sh_ex = ex;
        __hip_atomic_store(&lb->desc[tkt], (2ULL << 62) | (u64)(unsigned)(ex + S), __ATOMIC_RELEASE, AGENT);
    }
    __syncthreads();
    int run = sh_ex + lex;
#pragma unroll
    for (int j = 0; j < 4; ++j) {
        int ii = idx0 + j;
        if (ii < n) { offp[ii] = run; cursor[ii] = 0; }
        run += v[j];
    }
}

// CSR scatter (list order race-dependent; all consumers are commutative sums -> deterministic)
__global__ void k_scatter(const int* __restrict__ src, const int* __restrict__ dst,
                          const int* __restrict__ offp, int* __restrict__ cursor,
                          int* __restrict__ adj, int E) {
    int e = blockIdx.x * blockDim.x + threadIdx.x;
    if (e >= E) return;
    int d = dst[e];
    int pos = atomicAdd(&cursor[d], 1);
    adj[offp[d] + pos] = src[e];
}

// per-node multiset hash via LDS-tiled COALESCED adj gather (block's adj range is contiguous),
// then CAS-table group insert. fused: zero sumsq.
__global__ void __launch_bounds__(256) k_hashinsert(
        const int* __restrict__ col, const int* __restrict__ deg,
        const int* __restrict__ offp, const int* __restrict__ adj,
        u64* __restrict__ ktab, int* __restrict__ gmin, int* __restrict__ nodeslot,
        float* __restrict__ sumsq, int n, int E) {
    __shared__ int lds[ACHUNK];
    int t = threadIdx.x;
    int i = blockIdx.x * 256 + t;
    int T = gridDim.x * 256;
    for (int j = i; j < n; j += T) sumsq[j] = 0.f;
    int first = blockIdx.x * 256;
    if (first >= n) return;
    int lastN = first + 256 < n ? first + 256 : n;
    int rs = offp[first];
    int re = (lastN < n) ? offp[lastN] : E;
    int s0 = 0, e0 = 0, dg = 0;
    if (i < n) { s0 = offp[i]; dg = deg[i]; e0 = s0 + dg; }
    u64 h = 0ULL;
    for (int cs = rs; cs < re; cs += ACHUNK) {
        int ce = cs + ACHUNK < re ? cs + ACHUNK : re;
        __syncthreads();
        for (int j = cs + t; j < ce; j += 256) lds[j - cs] = adj[j];  // coalesced
        __syncthreads();
        if (i < n) {
            int a = s0 > cs ? s0 : cs, b = e0 < ce ? e0 : ce;
            for (int k = a; k < b; ++k) {
                u64 c = (u64)(unsigned)col[lds[k - cs]];
                h += mix64(c ^ 0x5bf03635c1d4aeb1ULL);  // commutative -> order-free
            }
        }
    }
    if (i >= n) return;
    u64 bb = mix64((u64)(unsigned)col[i] + 0x0123456789abcdefULL);
    u64 cc = mix64((u64)(unsigned)dg + 0xfedcba9876543210ULL);
    u64 sig = mix64(h + bb * 0x9e3779b97f4a7c15ULL + cc * 0xc2b2ae3d27d4eb4fULL);
    if (!sig) sig = 1;
    unsigned slot = (unsigned)sig & HMASK;
    for (;;) {
        u64 p = atomicCAS(&ktab[slot], 0ULL, sig);
        if (p == 0ULL || p == sig) break;
        slot = (slot + 1) & HMASK;
    }
    nodeslot[i] = slot;
    atomicMin(&gmin[slot], i);
}

// fused: leader flags -> lookback scan -> appearance-order colors -> histogram + row sumsq.
// requires all nb blocks co-resident (nb<=128 << 256 CUs) for the nc publish/wait.
__global__ void k_scanhist(const int* __restrict__ nodeslot, const int* __restrict__ gmin,
                           const int* __restrict__ batch, const float* __restrict__ w,
                           int* __restrict__ rankv, int* __restrict__ nxt,
                           float* __restrict__ out, float* __restrict__ sumsq,
                           float* __restrict__ oldv, long long* __restrict__ scalars,
                           int layer, LB* __restrict__ lb, int n, int nb) {
    __shared__ int s[256];
    __shared__ int sh_tkt, sh_ex, rbase_s;
    __shared__ long long sh_nc, sh_base;
    __shared__ float ssq[64];
    int t = threadIdx.x;
    if (t == 0) sh_tkt = atomicAdd(&lb->ctrs[0], 1);
    if (t < 64) ssq[t] = 0.f;
    __syncthreads();
    int tkt = sh_tkt;
    int idx0 = tkt * SCHUNK + t * 4;
    int g4[4]; int v[4]; int sum = 0;
#pragma unroll
    for (int j = 0; j < 4; ++j) {
        int ii = idx0 + j;
        if (ii < n) { int g = gmin[nodeslot[ii]]; g4[j] = g; v[j] = (g == ii) ? 1 : 0; }
        else { g4[j] = 0; v[j] = 0; }
        sum += v[j];
    }
    s[t] = sum; __syncthreads();
    for (int off = 1; off < 256; off <<= 1) {
        int x = (t >= off) ? s[t - off] : 0;
        __syncthreads(); s[t] += x; __syncthreads();
    }
    int lex = s[t] - sum;
    int S = s[255];
    if (t == 0) {
        __hip_atomic_store(&lb->desc[tkt], (1ULL << 62) | (u64)(unsigned)S, __ATOMIC_RELEASE, AGENT);
        int ex = 0;
        for (int b = tkt - 1; b >= 0;) {
            u64 d = __hip_atomic_load(&lb->desc[b], __ATOMIC_ACQUIRE, AGENT);
            unsigned st = (unsigned)(d >> 62);
            if (st == 2u) { ex += (int)(d & 0xffffffffu); break; }
            if (st == 1u) { ex += (int)(d & 0xffffffffu); --b; }
        }
        sh_ex = ex;
        __hip_atomic_store(&lb->desc[tkt], (2ULL << 62) | (u64)(unsigned)(ex + S), __ATOMIC_RELEASE, AGENT);
        if (tkt == nb - 1) {  // last ticket knows the grand total = nc
            long long total = ex + S;
            scalars[layer] = total;
            long long bsize = (long long)batch[n - 1] + 1;  // batch sorted
            scalars[4 + layer] = scalars[3 + layer] + bsize * total;
            __hip_atomic_store(&lb->ctrs[1], 1, __ATOMIC_RELEASE, AGENT);
        }
    }
    __syncthreads();
    int run = sh_ex + lex;
#pragma unroll
    for (int j = 0; j < 4; ++j) { int ii = idx0 + j; if (ii < n) rankv[ii] = run; run += v[j]; }
    __threadfence();
    __syncthreads();
    if (t == 0) {
        __hip_atomic_store(&lb->done[tkt], 1, __ATOMIC_RELEASE, AGENT);
        while (!__hip_atomic_load(&lb->ctrs[1], __ATOMIC_ACQUIRE, AGENT)) {}
        sh_nc = scalars[layer];
        sh_base = scalars[3 + layer];
        int a = tkt * SCHUNK;
        rbase_s = batch[a < n ? a : n - 1];
    }
    __syncthreads();
    long long nc = sh_nc, base = sh_base;
#pragma unroll
    for (int j = 0; j < 4; ++j) {
        int ii = idx0 + j;
        if (ii >= n) continue;
        int g = g4[j];
        int cb = g >> 10;  // g <= ii -> cb <= tkt -> waits only downward
        if (cb != tkt) {
            while (!__hip_atomic_load(&lb->done[cb], __ATOMIC_ACQUIRE, AGENT)) {}
        }
        int c = rankv[g];
        nxt[ii] = c;
        int r = batch[ii];
        long long idx = base + (long long)r * nc + c;
        float wi = w[ii];
        float old = atomicAdd(&out[idx], wi);
        oldv[ii] = old;
        float val = 2.f * old * wi + wi * wi;  // exact ints -> order-free
        int sl = r - rbase_s;
        if (sl >= 0 && sl < 64) atomicAdd(&ssq[sl], val);
        else atomicAdd(&sumsq[r], val);
    }
    __syncthreads();
    if (t < 64 && ssq[t] != 0.f) atomicAdd(&sumsq[rbase_s + t], ssq[t]);
}

// owners (saw old==0) normalize; fused: zero tables + the next layer's lookback set
__global__ void k_norm(const int* __restrict__ batch, const int* __restrict__ col,
                       float* __restrict__ out, const float* __restrict__ sumsq,
                       const float* __restrict__ oldv,
                       const long long* __restrict__ scalars, int layer,
                       u64* __restrict__ ktab, int* __restrict__ gmin,
                       LB* __restrict__ lbz, int n) {
    int i = blockIdx.x * blockDim.x + threadIdx.x;
    int T = gridDim.x * blockDim.x;
    for (int j = i; j < (int)HSLOTS; j += T) { ktab[j] = 0ULL; gmin[j] = 0x7fffffff; }
    if (i < 128) { lbz->desc[i] = 0ULL; lbz->done[i] = 0; }
    if (i < 4) lbz->ctrs[i] = 0;
    if (i >= n) return;
    if (oldv[i] != 0.f) return;
    int r = batch[i];
    long long idx = scalars[3 + layer] + (long long)r * scalars[layer] + col[i];
    out[idx] = out[idx] / sqrtf(sumsq[r]);
}

extern "C" void kernel_launch(void* const* d_in, const int* in_sizes, int n_in,
                              void* d_out, int out_size, void* d_ws, size_t ws_size,
                              hipStream_t stream) {
    const int* x = (const int*)d_in[0];
    const int* ei = (const int*)d_in[1];
    const int* batch = (const int*)d_in[2];
    const float* w = (const float*)d_in[3];
    int N = in_sizes[0];
    int E = in_sizes[1] / 2;
    const int* src = ei;
    const int* dst = ei + E;

    // workspace carve (~19.5 MB)
    char* p = (char*)d_ws;
    u64* ktab = (u64*)p;                p += (size_t)HSLOTS * 8;
    LB* lbA = (LB*)p;                   p += sizeof(LB);
    LB* lbB = (LB*)p;                   p += sizeof(LB);
    long long* scalars = (long long*)p; p += 8 * 8;
    int* adj      = (int*)p;            p += (size_t)E * 4;
    int* deg      = (int*)p;            p += (size_t)N * 4;
    int* cursor   = (int*)p;            p += (size_t)N * 4;
    int* offp     = (int*)p;            p += (size_t)N * 4;
    int* gmin     = (int*)p;            p += (size_t)HSLOTS * 4;
    int* nodeslot = (int*)p;            p += (size_t)N * 4;
    int* rankv    = (int*)p;            p += (size_t)N * 4;
    int* colA     = (int*)p;            p += (size_t)N * 4;
    int* colB     = (int*)p;            p += (size_t)N * 4;
    float* oldv   = (float*)p;          p += (size_t)N * 4;
    float* sumsq  = (float*)p;          p += (size_t)N * 4;
    if ((size_t)(p - (char*)d_ws) > ws_size) return;

    int gN = (N + 255) / 256;
    int gE = (E + 255) / 256;
    int nb = (N + SCHUNK - 1) / SCHUNK;
    if (nb > 128) return;  // lookback descriptor capacity (N<=131072)

    k_setup<<<gN, 256, 0, stream>>>(deg, lbA, lbB, scalars, N);
    k_count<<<gE, 256, 0, stream>>>(dst, deg, ktab, gmin,
                                    (float*)d_out, (long long)out_size, E);
    k_scanoff<<<nb, 256, 0, stream>>>(deg, offp, cursor, lbA, N);
    k_scatter<<<gE, 256, 0, stream>>>(src, dst, offp, cursor, adj, E);

    const int* cur = x;
    int* nxt = colA;
    for (int l = 0; l < WL_LAYERS; ++l) {
        LB* lbScan = (l == 1) ? lbA : lbB;           // l=0:B, l=1:A, l=2:B
        LB* lbZero = (l == 0) ? lbA : lbB;           // zero the set layer l+1 will use
        k_hashinsert<<<gN, 256, 0, stream>>>(cur, deg, offp, adj, ktab, gmin,
                                             nodeslot, sumsq, N, E);
        k_scanhist<<<nb, 256, 0, stream>>>(nodeslot, gmin, batch, w, rankv, nxt,
                                           (float*)d_out, sumsq, oldv, scalars, l,
                                           lbScan, N, nb);
        k_norm<<<gN, 256, 0, stream>>>(batch, nxt, (float*)d_out, sumsq, oldv,
                                       scalars, l, ktab, gmin, lbZero, N);
        cur = nxt;
        nxt = (l == 0) ? colB : colA;
    }
}

// Round 5
// 509.317 us; speedup vs baseline: 1.1803x; 1.1803x over previous
//
#include <hip/hip_runtime.h>
#include <math.h>

#define WL_LAYERS 3
#define HSLOTS (1u << 18)
#define HMASK  (HSLOTS - 1u)
#define SCHUNK 1024   // elements per scan block
#define ACHUNK 8192   // adj entries staged in LDS (32 KB)

typedef unsigned long long u64;

__device__ __forceinline__ u64 mix64(u64 x) {
    x += 0x9e3779b97f4a7c15ULL;
    x = (x ^ (x >> 30)) * 0xbf58476d1ce4e5b9ULL;
    x = (x ^ (x >> 27)) * 0x94d049bb133111ebULL;
    return x ^ (x >> 31);
}

// zero deg/cursor/done-counters; base[0]=0
__global__ void k_setup(int* __restrict__ deg, int* __restrict__ cursor,
                        int* __restrict__ dcnt, long long* __restrict__ scalars, int n) {
    int i = blockIdx.x * blockDim.x + threadIdx.x;
    int T = gridDim.x * blockDim.x;
    for (int j = i; j < n; j += T) { deg[j] = 0; cursor[j] = 0; }
    if (i < 8) dcnt[i] = 0;
    if (i == 0) scalars[3] = 0;
}

// in-degree count; fused one-shot zero of 614MB d_out + ALL 3 layers' tables/sumsq
__global__ void k_count(const int* __restrict__ dst, int* __restrict__ deg,
                        u64* __restrict__ ktabs, int* __restrict__ gmins,
                        float* __restrict__ sumsqs, float* __restrict__ zbuf,
                        long long zn, int n, int E) {
    int tid = blockIdx.x * blockDim.x + threadIdx.x;
    int T = gridDim.x * blockDim.x;
    int HT = 3 * (int)HSLOTS;
    for (int j = tid; j < HT; j += T) { ktabs[j] = 0ULL; gmins[j] = 0x7fffffff; }
    for (int j = tid; j < 3 * n; j += T) sumsqs[j] = 0.f;
    long long n4 = zn >> 2;
    float4* z4 = (float4*)zbuf;
    for (long long j = tid; j < n4; j += (long long)T)
        z4[j] = make_float4(0.f, 0.f, 0.f, 0.f);
    if (tid < (int)(zn & 3)) zbuf[(n4 << 2) + tid] = 0.f;
    if (tid < E) atomicAdd(&deg[dst[tid]], 1);
}

// block-local exclusive scan of deg -> offp; last finishing block scans the <=128
// block sums in place (all blocks parallel, no cross-block spins)
__global__ void k_scanoff(const int* __restrict__ deg, int* __restrict__ offp,
                          int* __restrict__ obsum, int* __restrict__ dcnt, int n, int nb) {
    __shared__ int s[256];
    __shared__ int sh_last;
    int t = threadIdx.x;
    int idx0 = blockIdx.x * SCHUNK + t * 4;
    int v[4]; int sum = 0;
#pragma unroll
    for (int j = 0; j < 4; ++j) { int ii = idx0 + j; v[j] = (ii < n) ? deg[ii] : 0; sum += v[j]; }
    s[t] = sum; __syncthreads();
    for (int off = 1; off < 256; off <<= 1) {
        int x = (t >= off) ? s[t - off] : 0;
        __syncthreads(); s[t] += x; __syncthreads();
    }
    int run = s[t] - sum;
#pragma unroll
    for (int j = 0; j < 4; ++j) { int ii = idx0 + j; if (ii < n) offp[ii] = run; run += v[j]; }
    if (t == 255) obsum[blockIdx.x] = s[255];
    __threadfence();
    if (t == 0) sh_last = (atomicAdd(&dcnt[0], 1) == gridDim.x - 1);
    __syncthreads();
    if (sh_last) {
        __threadfence();
        int v2 = (t < nb) ? obsum[t] : 0;
        __syncthreads();
        s[t] = v2; __syncthreads();
        for (int off = 1; off < 256; off <<= 1) {
            int x = (t >= off) ? s[t - off] : 0;
            __syncthreads(); s[t] += x; __syncthreads();
        }
        if (t < nb) obsum[t] = s[t] - v2;
    }
}

// CSR scatter (list order race-dependent; all consumers are commutative sums -> deterministic)
__global__ void k_scatter(const int* __restrict__ src, const int* __restrict__ dst,
                          const int* __restrict__ offp, const int* __restrict__ obsum,
                          int* __restrict__ cursor, int* __restrict__ adj, int E) {
    int e = blockIdx.x * blockDim.x + threadIdx.x;
    if (e >= E) return;
    int d = dst[e];
    int pos = atomicAdd(&cursor[d], 1);
    adj[offp[d] + obsum[d >> 10] + pos] = src[e];
}

// shared body: per-node multiset hash via LDS-tiled COALESCED adj gather
// (block's absolute adj range is contiguous), then CAS-table group insert
__device__ __forceinline__ void hash_insert_body(
        int* lds, const int* __restrict__ col, const int* __restrict__ deg,
        const int* __restrict__ offp, const int* __restrict__ obsum,
        const int* __restrict__ adj, u64* __restrict__ ktab, int* __restrict__ gmin,
        int* __restrict__ nodeslot, int n, int E) {
    int t = threadIdx.x;
    int first = blockIdx.x * 256;
    if (first >= n) return;                 // block-uniform
    int i = first + t;
    int lastN = first + 256 < n ? first + 256 : n;
    int rs = offp[first] + obsum[first >> 10];
    int re = (lastN < n) ? offp[lastN] + obsum[lastN >> 10] : E;
    int s0 = 0, e0 = 0, dg = 0;
    if (i < n) { s0 = offp[i] + obsum[i >> 10]; dg = deg[i]; e0 = s0 + dg; }
    u64 h = 0ULL;
    for (int cs = rs; cs < re; cs += ACHUNK) {
        int ce = cs + ACHUNK < re ? cs + ACHUNK : re;
        __syncthreads();
        for (int j = cs + t; j < ce; j += 256) lds[j - cs] = adj[j];  // coalesced
        __syncthreads();
        if (i < n) {
            int a = s0 > cs ? s0 : cs, b = e0 < ce ? e0 : ce;
            for (int k = a; k < b; ++k) {
                u64 c = (u64)(unsigned)col[lds[k - cs]];
                h += mix64(c ^ 0x5bf03635c1d4aeb1ULL);  // commutative -> order-free
            }
        }
    }
    if (i >= n) return;
    u64 bb = mix64((u64)(unsigned)col[i] + 0x0123456789abcdefULL);
    u64 cc = mix64((u64)(unsigned)dg + 0xfedcba9876543210ULL);
    u64 sig = mix64(h + bb * 0x9e3779b97f4a7c15ULL + cc * 0xc2b2ae3d27d4eb4fULL);
    if (!sig) sig = 1;
    unsigned slot = (unsigned)sig & HMASK;
    for (;;) {
        u64 p = atomicCAS(&ktab[slot], 0ULL, sig);
        if (p == 0ULL || p == sig) break;
        slot = (slot + 1) & HMASK;
    }
    nodeslot[i] = slot;
    atomicMin(&gmin[slot], i);
}

__global__ void __launch_bounds__(256) k_hashinsert(
        const int* __restrict__ col, const int* __restrict__ deg,
        const int* __restrict__ offp, const int* __restrict__ obsum,
        const int* __restrict__ adj, u64* __restrict__ ktab, int* __restrict__ gmin,
        int* __restrict__ nodeslot, int n, int E) {
    __shared__ int lds[ACHUNK];
    hash_insert_body(lds, col, deg, offp, obsum, adj, ktab, gmin, nodeslot, n, E);
}

// leader flags -> block-local scan -> last block scans partials + publishes nc/base
__global__ void k_scanF(const int* __restrict__ nodeslot, const int* __restrict__ gmin,
                        int* __restrict__ rankv, int* __restrict__ bsum,
                        int* __restrict__ dcnt, long long* __restrict__ scalars,
                        int layer, const int* __restrict__ batch, int n, int nb) {
    __shared__ int s[256];
    __shared__ int sh_last;
    int t = threadIdx.x;
    int idx0 = blockIdx.x * SCHUNK + t * 4;
    int v[4]; int sum = 0;
#pragma unroll
    for (int j = 0; j < 4; ++j) {
        int ii = idx0 + j;
        v[j] = (ii < n && gmin[nodeslot[ii]] == ii) ? 1 : 0;
        sum += v[j];
    }
    s[t] = sum; __syncthreads();
    for (int off = 1; off < 256; off <<= 1) {
        int x = (t >= off) ? s[t - off] : 0;
        __syncthreads(); s[t] += x; __syncthreads();
    }
    int run = s[t] - sum;
#pragma unroll
    for (int j = 0; j < 4; ++j) { int ii = idx0 + j; if (ii < n) rankv[ii] = run; run += v[j]; }
    if (t == 255) bsum[blockIdx.x] = s[255];
    __threadfence();
    if (t == 0) sh_last = (atomicAdd(&dcnt[0], 1) == gridDim.x - 1);
    __syncthreads();
    if (sh_last) {
        __threadfence();
        int v2 = (t < nb) ? bsum[t] : 0;
        __syncthreads();
        s[t] = v2; __syncthreads();
        for (int off = 1; off < 256; off <<= 1) {
            int x = (t >= off) ? s[t - off] : 0;
            __syncthreads(); s[t] += x; __syncthreads();
        }
        if (t < nb) bsum[t] = s[t] - v2;
        if (t == 255) {
            long long total = s[255];
            scalars[layer] = total;                         // nc
            long long bsize = (long long)batch[n - 1] + 1;  // batch sorted
            scalars[4 + layer] = scalars[3 + layer] + bsize * total;
        }
    }
}

// color = rankv[g] + bsum[g>>10]; histogram scatter + LDS-aggregated row sumsq
// (all fp adds are exact integers -> order-free)
__global__ void k_hist(const int* __restrict__ batch, const int* __restrict__ nodeslot,
                       const int* __restrict__ gmin, const int* __restrict__ rankv,
                       const int* __restrict__ bsum, int* __restrict__ nxt,
                       const float* __restrict__ w, float* __restrict__ out,
                       float* __restrict__ sumsq, float* __restrict__ oldv,
                       const long long* __restrict__ scalars, int layer, int n) {
    __shared__ float ssq[64];
    __shared__ int rbase_s;
    int t = threadIdx.x;
    int i = blockIdx.x * 256 + t;
    if (t < 64) ssq[t] = 0.f;
    if (t == 0) {
        int a = blockIdx.x * 256;
        rbase_s = batch[a < n ? a : n - 1];
    }
    __syncthreads();
    if (i < n) {
        int g = gmin[nodeslot[i]];
        int c = rankv[g] + bsum[g >> 10];
        nxt[i] = c;
        int r = batch[i];
        long long idx = scalars[3 + layer] + (long long)r * scalars[layer] + c;
        float wi = w[i];
        float old = atomicAdd(&out[idx], wi);
        oldv[i] = old;
        float val = 2.f * old * wi + wi * wi;
        int sl = r - rbase_s;
        if (sl >= 0 && sl < 64) atomicAdd(&ssq[sl], val);
        else atomicAdd(&sumsq[r], val);
    }
    __syncthreads();
    if (t < 64 && ssq[t] != 0.f) atomicAdd(&sumsq[rbase_s + t], ssq[t]);
}

// fused: normalize layer l-1 (owners only) + hash-insert layer l (independent work)
__global__ void __launch_bounds__(256) k_normhash(
        const int* __restrict__ batch, const int* __restrict__ col,
        float* __restrict__ out, const float* __restrict__ sumsq_prev,
        const float* __restrict__ oldv, const long long* __restrict__ scalars,
        int layerPrev, const int* __restrict__ deg, const int* __restrict__ offp,
        const int* __restrict__ obsum, const int* __restrict__ adj,
        u64* __restrict__ ktab, int* __restrict__ gmin, int* __restrict__ nodeslot,
        int n, int E) {
    __shared__ int lds[ACHUNK];
    int i = blockIdx.x * 256 + threadIdx.x;
    if (i < n && oldv[i] == 0.f) {  // owner of this histogram cell
        int r = batch[i];
        long long idx = scalars[3 + layerPrev] + (long long)r * scalars[layerPrev] + col[i];
        out[idx] = out[idx] / sqrtf(sumsq_prev[r]);
    }
    hash_insert_body(lds, col, deg, offp, obsum, adj, ktab, gmin, nodeslot, n, E);
}

// plain normalize for the last layer
__global__ void k_norm(const int* __restrict__ batch, const int* __restrict__ col,
                       float* __restrict__ out, const float* __restrict__ sumsq,
                       const float* __restrict__ oldv,
                       const long long* __restrict__ scalars, int layer, int n) {
    int i = blockIdx.x * blockDim.x + threadIdx.x;
    if (i >= n) return;
    if (oldv[i] != 0.f) return;
    int r = batch[i];
    long long idx = scalars[3 + layer] + (long long)r * scalars[layer] + col[i];
    out[idx] = out[idx] / sqrtf(sumsq[r]);
}

extern "C" void kernel_launch(void* const* d_in, const int* in_sizes, int n_in,
                              void* d_out, int out_size, void* d_ws, size_t ws_size,
                              hipStream_t stream) {
    const int* x = (const int*)d_in[0];
    const int* ei = (const int*)d_in[1];
    const int* batch = (const int*)d_in[2];
    const float* w = (const float*)d_in[3];
    int N = in_sizes[0];
    int E = in_sizes[1] / 2;
    const int* src = ei;
    const int* dst = ei + E;

    // workspace carve (~26 MB): 3 table sets (one per layer, zeroed once)
    char* p = (char*)d_ws;
    u64* ktabs = (u64*)p;               p += (size_t)3 * HSLOTS * 8;
    long long* scalars = (long long*)p; p += 8 * 8;
    int* adj      = (int*)p;            p += (size_t)E * 4;
    int* gmins    = (int*)p;            p += (size_t)3 * HSLOTS * 4;
    int* deg      = (int*)p;            p += (size_t)N * 4;
    int* cursor   = (int*)p;            p += (size_t)N * 4;
    int* offp     = (int*)p;            p += (size_t)N * 4;
    int* nodeslot = (int*)p;            p += (size_t)N * 4;
    int* rankv    = (int*)p;            p += (size_t)N * 4;
    int* colA     = (int*)p;            p += (size_t)N * 4;
    int* colB     = (int*)p;            p += (size_t)N * 4;
    float* oldv   = (float*)p;          p += (size_t)N * 4;
    float* sumsqs = (float*)p;          p += (size_t)3 * N * 4;
    int* obsum    = (int*)p;            p += 256 * 4;
    int* bsum     = (int*)p;            p += 256 * 4;
    int* dcnt     = (int*)p;            p += 8 * 4;
    if ((size_t)(p - (char*)d_ws) > ws_size) return;

    int gN = (N + 255) / 256;
    int gE = (E + 255) / 256;
    int nb = (N + SCHUNK - 1) / SCHUNK;
    if (nb > 256) return;  // partial-sum array capacity (N<=262144)

    k_setup<<<gN, 256, 0, stream>>>(deg, cursor, dcnt, scalars, N);
    k_count<<<gE, 256, 0, stream>>>(dst, deg, ktabs, gmins, sumsqs,
                                    (float*)d_out, (long long)out_size, N, E);
    k_scanoff<<<nb, 256, 0, stream>>>(deg, offp, obsum, dcnt, N, nb);
    k_scatter<<<gE, 256, 0, stream>>>(src, dst, offp, obsum, cursor, adj, E);
    k_hashinsert<<<gN, 256, 0, stream>>>(x, deg, offp, obsum, adj,
                                         ktabs, gmins, nodeslot, N, E);

    const int* cur = x;
    int* nxt = colA;
    for (int l = 0; l < WL_LAYERS; ++l) {
        u64* kt = ktabs + (size_t)l * HSLOTS;
        int* gm = gmins + (size_t)l * HSLOTS;
        float* sq = sumsqs + (size_t)l * N;
        k_scanF<<<nb, 256, 0, stream>>>(nodeslot, gm, rankv, bsum, dcnt + 1 + l,
                                        scalars, l, batch, N, nb);
        k_hist<<<gN, 256, 0, stream>>>(batch, nodeslot, gm, rankv, bsum, nxt, w,
                                       (float*)d_out, sq, oldv, scalars, l, N);
        if (l < WL_LAYERS - 1) {
            k_normhash<<<gN, 256, 0, stream>>>(batch, nxt, (float*)d_out, sq, oldv,
                                               scalars, l, deg, offp, obsum, adj,
                                               kt + HSLOTS, gm + HSLOTS, nodeslot, N, E);
        } else {
            k_norm<<<gN, 256, 0, stream>>>(batch, nxt, (float*)d_out, sq, oldv,
                                           scalars, l, N);
        }
        cur = nxt;
        nxt = (l == 0) ? colB : colA;
    }
}